// Round 2
// baseline (106.051 us; speedup 1.0000x reference)
//
#include <hip/hip_runtime.h>

// PiecewisePolynomial: out[b,o] = sum_i sum_j L_j(x_in(b,i)) * w[o, i, 3*seg(b,i)+j]
// B=512, IN_F=256, OUT_F=256, SEGMENTS=16, N=4 (nodes -1,-0.5,0.5,1)
//
// R8: (a) pp_partial widened to 512 threads / 128 b per block (8 waves =
// 4 o-subranges x 2 b-halves sharing one 64KB staged slice) -> we read
// traffic halves 64->32 MB, grid 512 blocks = exactly 2/CU one round.
// (b) pp_reduce eliminated: partial atomically accumulates its transposed
// tile into out (out zeroed by a cheap prologue in pp_expand; same-stream
// ordering). part workspace gone. 2 dispatches instead of 3.

typedef _Float16 h2 __attribute__((ext_vector_type(2)));

#define INF     256
#define OUTF    256
#define WSTRIDE 49
#define OSTRIDE (INF * WSTRIDE)       // 12544
#define NSPLIT  16
#define IPB     16
#define WE_UINTS (256 * 128 * 64)     // 2,097,152 uints = 8.39 MB

#define GLOAD16(gptr, lptr)                                                         \
  __builtin_amdgcn_global_load_lds(                                                 \
      (const __attribute__((address_space(1))) unsigned int*)(gptr),                \
      (__attribute__((address_space(3))) unsigned int*)(lptr), 16, 0, 0)

// ---- expand: block = one o-pair (op) x half the i range. Stage contiguous
// w rows into LDS (coalesced 16B), convert, write we[i][op][s] 16B units in
// contiguous 256B runs. we[i][op][s] = {e0 pair0, e0 pair1, e1 pair0, e1 pair1},
// pair0 = f16x2(w[3s],w[3s+1]), pair1 = f16x2(w[3s+2],w[3s+3]).
// Also zeroes out[] (2 floats/thread) so pp_partial can atomically accumulate.
__global__ __launch_bounds__(256)
void pp_expand(const float* __restrict__ w, unsigned int* __restrict__ we,
               float* __restrict__ out) {
    __shared__ float lds_w[2][3136];      // 2 o x 64 i x 49 f32 = 25 KB

    const int tid   = threadIdx.x;

    // zero the output accumulator: 256 blk x 256 thr x 2 = 131072 floats
    {
        size_t idx = ((size_t)blockIdx.x * 256 + tid) * 2;
        *(float2*)(out + idx) = make_float2(0.f, 0.f);
    }

    const int op    = blockIdx.x >> 1;    // 0..127
    const int ihalf = blockIdx.x & 1;     // 0..1
    const int o0    = op * 2;

    for (int c = 0; c < 2; ++c) {
        const int i_c = ihalf * 128 + c * 64;     // i chunk base (64 i's)

        // stage: 2 x 784 float4, coalesced, 16B-aligned (64*49 floats = 12544B)
        #pragma unroll
        for (int oe = 0; oe < 2; ++oe) {
            const float* src = w + (size_t)(o0 + oe) * OSTRIDE + (size_t)i_c * WSTRIDE;
            #pragma unroll
            for (int it = 0; it < 4; ++it) {
                int u = it * 256 + tid;           // float4 index 0..1023
                if (u < 784)
                    GLOAD16(src + u * 4, &lds_w[oe][u * 4]);
            }
        }
        __syncthreads();   // drains vmcnt -> LDS valid

        // convert: 64 i x 16 s items; lanes walk s fastest -> 16B stores form
        // contiguous 256B runs per i.
        #pragma unroll
        for (int r = 0; r < 4; ++r) {
            int item = r * 256 + tid;             // 0..1023
            int il = item >> 4, s = item & 15;
            const float* t0 = &lds_w[0][il * 49 + 3 * s];
            const float* t1 = &lds_w[1][il * 49 + 3 * s];
            uint4 v;
            v.x = __builtin_bit_cast(unsigned int,
                      __builtin_amdgcn_cvt_pkrtz(t0[0], t0[1]));
            v.y = __builtin_bit_cast(unsigned int,
                      __builtin_amdgcn_cvt_pkrtz(t0[2], t0[3]));
            v.z = __builtin_bit_cast(unsigned int,
                      __builtin_amdgcn_cvt_pkrtz(t1[0], t1[1]));
            v.w = __builtin_bit_cast(unsigned int,
                      __builtin_amdgcn_cvt_pkrtz(t1[2], t1[3]));
            *(uint4*)(we + (((size_t)(i_c + il) * 128 + op) * 16 + s) * 4) = v;
        }
        __syncthreads();   // before overwriting lds_w with next chunk
    }
}

// ---- partial: 512 threads, 8 waves = 4 o-subranges x 2 b-halves.
// One 64KB staged slice serves 128 batch rows (was 64) -> we traffic halves.
// Epilogue: LDS transpose then coalesced atomicAdd into out.
__global__ __launch_bounds__(512, 4)
void pp_partial(const float* __restrict__ x, const unsigned int* __restrict__ we,
                float* __restrict__ out) {
    __shared__ unsigned int smem[16384];  // 16i x 16op x 16s x 16B = 64 KB

    const int tid  = threadIdx.x;
    const int wave = tid >> 6, lane = tid & 63;
    const int osub = wave & 3;                 // o-subrange within the 32-o tile
    const int bsub = wave >> 2;                // b-half within the 128-b tile
    const int isplit  = blockIdx.x;            // 0..15
    const int i_base  = isplit * IPB;          // *16
    const int op_base = blockIdx.y * 16;       // o_base = blockIdx.y*32
    const int o_base  = blockIdx.y * 32;
    const int b_base  = blockIdx.z * 128;
    const int b = b_base + bsub * 64 + lane;   // this lane's batch row

    // ---- single stage: whole 64KB slice, 8x 16B per thread, coalesced ----
    #pragma unroll
    for (int it = 0; it < 8; ++it) {
        int u = it * 512 + tid;                // 16B unit 0..4095
        int iloc = u >> 8, opl = (u >> 4) & 15, s = u & 15;
        const unsigned int* gp =
            we + (((size_t)(i_base + iloc) * 128 + op_base + opl) * 16 + s) * 4;
        GLOAD16(gp, &smem[u * 4]);
    }

    // ---- per-lane basis + segment for own b (overlaps with stage in flight) ----
    int sseg[IPB]; h2 cA[IPB], cB[IPB];
    {
        const float4* xp = (const float4*)(x + (size_t)b * INF + i_base);
        float4 x0 = xp[0], x1 = xp[1], x2 = xp[2], x3 = xp[3];
        float xs[16] = {x0.x, x0.y, x0.z, x0.w, x1.x, x1.y, x1.z, x1.w,
                        x2.x, x2.y, x2.z, x2.w, x3.x, x3.y, x3.z, x3.w};
        #pragma unroll
        for (int i = 0; i < IPB; ++i) {
            float xx = xs[i];
            int id = (int)((xx + 1.0f) * 8.0f);
            id = id < 0 ? 0 : (id > 15 ? 15 : id);
            float u = (xx - ((float)id * 0.125f - 1.0f)) * 16.0f - 1.0f;
            float a = u + 1.0f, b2 = u + 0.5f, cc = u - 0.5f, d = u - 1.0f;
            float c0 = b2 * cc * d  * (-2.0f / 3.0f);
            float c1 = a  * cc * d  * ( 4.0f / 3.0f);
            float c2 = a  * b2 * d  * (-4.0f / 3.0f);
            float c3 = a  * b2 * cc * ( 2.0f / 3.0f);
            h2 pA; pA[0] = (_Float16)c0; pA[1] = (_Float16)c1;
            h2 pB; pB[0] = (_Float16)c2; pB[1] = (_Float16)c3;
            cA[i] = pA; cB[i] = pB; sseg[i] = id;
        }
    }

    __syncthreads();    // THE one barrier: stage drained, LDS valid

    // ---- uninterrupted compute: 64 ds_read_b128 + 256 fdot2 per lane ----
    // wave covers o = o_base + osub*8 .. +7  (op = osub*4 + pq)
    float acc[8];
    #pragma unroll
    for (int q = 0; q < 8; ++q) acc[q] = 0.0f;

    #pragma unroll
    for (int i = 0; i < IPB; ++i) {
        const unsigned int* p = &smem[(i * 16 + osub * 4) * 64 + sseg[i] * 4];
        #pragma unroll
        for (int pq = 0; pq < 4; ++pq) {
            uint4 v = *(const uint4*)(p + pq * 64);
            acc[2*pq]   = __builtin_amdgcn_fdot2(__builtin_bit_cast(h2, v.x), cA[i],
                                                 acc[2*pq],   false);
            acc[2*pq]   = __builtin_amdgcn_fdot2(__builtin_bit_cast(h2, v.y), cB[i],
                                                 acc[2*pq],   false);
            acc[2*pq+1] = __builtin_amdgcn_fdot2(__builtin_bit_cast(h2, v.z), cA[i],
                                                 acc[2*pq+1], false);
            acc[2*pq+1] = __builtin_amdgcn_fdot2(__builtin_bit_cast(h2, v.w), cB[i],
                                                 acc[2*pq+1], false);
        }
    }

    // ---- LDS transpose (lane=b -> lane=o) + coalesced atomic accumulate ----
    __syncthreads();                      // weights no longer needed
    float* smf = (float*)smem;            // [128 b][33] fp32 = 16.9 KB
    const int b_l0 = bsub * 64 + lane;
    #pragma unroll
    for (int q = 0; q < 8; ++q)
        smf[b_l0 * 33 + osub * 8 + q] = acc[q];
    __syncthreads();

    const int qo = tid & 7;               // o-quad 0..7 (4 floats each)
    const int g  = tid >> 3;              // 0..63
    #pragma unroll
    for (int r = 0; r < 2; ++r) {
        int b_l = g + 64 * r;
        float vx = smf[b_l * 33 + qo * 4 + 0];
        float vy = smf[b_l * 33 + qo * 4 + 1];
        float vz = smf[b_l * 33 + qo * 4 + 2];
        float vw = smf[b_l * 33 + qo * 4 + 3];
        float* dst = out + (size_t)(b_base + b_l) * 256 + o_base + qo * 4;
        atomicAdd(dst + 0, vx);
        atomicAdd(dst + 1, vy);
        atomicAdd(dst + 2, vz);
        atomicAdd(dst + 3, vw);
    }
}

extern "C" void kernel_launch(void* const* d_in, const int* in_sizes, int n_in,
                              void* d_out, int out_size, void* d_ws, size_t ws_size,
                              hipStream_t stream) {
    const float* x = (const float*)d_in[0];
    const float* w = (const float*)d_in[1];
    float* out = (float*)d_out;
    unsigned int* we = (unsigned int*)d_ws;                       // 8.39 MB
    (void)ws_size; (void)n_in; (void)in_sizes; (void)out_size;

    pp_expand<<<dim3(256), 256, 0, stream>>>(w, we, out);
    pp_partial<<<dim3(NSPLIT, 8, 4), 512, 0, stream>>>(x, we, out);
}

// Round 3
// 83.921 us; speedup vs baseline: 1.2637x; 1.2637x over previous
//
#include <hip/hip_runtime.h>

// PiecewisePolynomial: out[b,o] = sum_i sum_j L_j(x_in(b,i)) * w[o, i, 3*seg(b,i)+j]
// B=512, IN_F=256, OUT_F=256, SEGMENTS=16, N=4 (nodes -1,-0.5,0.5,1)
//
// R9: R8's widened pp_partial (512 thr / 128 b per block, one 64KB staged
// slice serves 128 rows -> we reads 64->32 MB, 4 waves/SIMD) BUT with R7's
// split-K part + pp_reduce epilogue (coalesced float4 stores). R8's
// atomicAdd epilogue was the regression (16-way same-address contention,
// ~+20 us) and is reverted.

typedef _Float16 h2 __attribute__((ext_vector_type(2)));

#define INF     256
#define OUTF    256
#define WSTRIDE 49
#define OSTRIDE (INF * WSTRIDE)       // 12544
#define NSPLIT  16
#define IPB     16
#define WE_UINTS (256 * 128 * 64)     // 2,097,152 uints = 8.39 MB

#define GLOAD16(gptr, lptr)                                                         \
  __builtin_amdgcn_global_load_lds(                                                 \
      (const __attribute__((address_space(1))) unsigned int*)(gptr),                \
      (__attribute__((address_space(3))) unsigned int*)(lptr), 16, 0, 0)

// ---- expand: block = one o-pair (op) x half the i range. Stage contiguous
// w rows into LDS (coalesced 16B), convert, write we[i][op][s] 16B units in
// contiguous 256B runs. we[i][op][s] = {e0 pair0, e0 pair1, e1 pair0, e1 pair1},
// pair0 = f16x2(w[3s],w[3s+1]), pair1 = f16x2(w[3s+2],w[3s+3]).
__global__ __launch_bounds__(256)
void pp_expand(const float* __restrict__ w, unsigned int* __restrict__ we) {
    __shared__ float lds_w[2][3136];      // 2 o x 64 i x 49 f32 = 25 KB

    const int tid   = threadIdx.x;
    const int op    = blockIdx.x >> 1;    // 0..127
    const int ihalf = blockIdx.x & 1;     // 0..1
    const int o0    = op * 2;

    for (int c = 0; c < 2; ++c) {
        const int i_c = ihalf * 128 + c * 64;     // i chunk base (64 i's)

        // stage: 2 x 784 float4, coalesced, 16B-aligned (64*49 floats = 12544B)
        #pragma unroll
        for (int oe = 0; oe < 2; ++oe) {
            const float* src = w + (size_t)(o0 + oe) * OSTRIDE + (size_t)i_c * WSTRIDE;
            #pragma unroll
            for (int it = 0; it < 4; ++it) {
                int u = it * 256 + tid;           // float4 index 0..1023
                if (u < 784)
                    GLOAD16(src + u * 4, &lds_w[oe][u * 4]);
            }
        }
        __syncthreads();   // drains vmcnt -> LDS valid

        // convert: 64 i x 16 s items; lanes walk s fastest -> 16B stores form
        // contiguous 256B runs per i.
        #pragma unroll
        for (int r = 0; r < 4; ++r) {
            int item = r * 256 + tid;             // 0..1023
            int il = item >> 4, s = item & 15;
            const float* t0 = &lds_w[0][il * 49 + 3 * s];
            const float* t1 = &lds_w[1][il * 49 + 3 * s];
            uint4 v;
            v.x = __builtin_bit_cast(unsigned int,
                      __builtin_amdgcn_cvt_pkrtz(t0[0], t0[1]));
            v.y = __builtin_bit_cast(unsigned int,
                      __builtin_amdgcn_cvt_pkrtz(t0[2], t0[3]));
            v.z = __builtin_bit_cast(unsigned int,
                      __builtin_amdgcn_cvt_pkrtz(t1[0], t1[1]));
            v.w = __builtin_bit_cast(unsigned int,
                      __builtin_amdgcn_cvt_pkrtz(t1[2], t1[3]));
            *(uint4*)(we + (((size_t)(i_c + il) * 128 + op) * 16 + s) * 4) = v;
        }
        __syncthreads();   // before overwriting lds_w with next chunk
    }
}

// ---- partial: 512 threads, 8 waves = 4 o-subranges x 2 b-halves.
// One 64KB staged slice serves 128 batch rows -> we traffic halves vs R7.
// Epilogue: LDS transpose then coalesced float4 stores into part.
__global__ __launch_bounds__(512, 4)
void pp_partial(const float* __restrict__ x, const unsigned int* __restrict__ we,
                float* __restrict__ part) {
    __shared__ unsigned int smem[16384];  // 16i x 16op x 16s x 16B = 64 KB

    const int tid  = threadIdx.x;
    const int wave = tid >> 6, lane = tid & 63;
    const int osub = wave & 3;                 // o-subrange within the 32-o tile
    const int bsub = wave >> 2;                // b-half within the 128-b tile
    const int isplit  = blockIdx.x;            // 0..15
    const int i_base  = isplit * IPB;          // *16
    const int op_base = blockIdx.y * 16;       // o_base = blockIdx.y*32
    const int o_base  = blockIdx.y * 32;
    const int b_base  = blockIdx.z * 128;
    const int b = b_base + bsub * 64 + lane;   // this lane's batch row

    // ---- single stage: whole 64KB slice, 8x 16B per thread, coalesced ----
    #pragma unroll
    for (int it = 0; it < 8; ++it) {
        int u = it * 512 + tid;                // 16B unit 0..4095
        int iloc = u >> 8, opl = (u >> 4) & 15, s = u & 15;
        const unsigned int* gp =
            we + (((size_t)(i_base + iloc) * 128 + op_base + opl) * 16 + s) * 4;
        GLOAD16(gp, &smem[u * 4]);
    }

    // ---- per-lane basis + segment for own b (overlaps with stage in flight) ----
    int sseg[IPB]; h2 cA[IPB], cB[IPB];
    {
        const float4* xp = (const float4*)(x + (size_t)b * INF + i_base);
        float4 x0 = xp[0], x1 = xp[1], x2 = xp[2], x3 = xp[3];
        float xs[16] = {x0.x, x0.y, x0.z, x0.w, x1.x, x1.y, x1.z, x1.w,
                        x2.x, x2.y, x2.z, x2.w, x3.x, x3.y, x3.z, x3.w};
        #pragma unroll
        for (int i = 0; i < IPB; ++i) {
            float xx = xs[i];
            int id = (int)((xx + 1.0f) * 8.0f);
            id = id < 0 ? 0 : (id > 15 ? 15 : id);
            float u = (xx - ((float)id * 0.125f - 1.0f)) * 16.0f - 1.0f;
            float a = u + 1.0f, b2 = u + 0.5f, cc = u - 0.5f, d = u - 1.0f;
            float c0 = b2 * cc * d  * (-2.0f / 3.0f);
            float c1 = a  * cc * d  * ( 4.0f / 3.0f);
            float c2 = a  * b2 * d  * (-4.0f / 3.0f);
            float c3 = a  * b2 * cc * ( 2.0f / 3.0f);
            h2 pA; pA[0] = (_Float16)c0; pA[1] = (_Float16)c1;
            h2 pB; pB[0] = (_Float16)c2; pB[1] = (_Float16)c3;
            cA[i] = pA; cB[i] = pB; sseg[i] = id;
        }
    }

    __syncthreads();    // THE one barrier: stage drained, LDS valid

    // ---- uninterrupted compute: 64 ds_read_b128 + 256 fdot2 per lane ----
    // wave covers o = o_base + osub*8 .. +7  (op = osub*4 + pq)
    float acc[8];
    #pragma unroll
    for (int q = 0; q < 8; ++q) acc[q] = 0.0f;

    #pragma unroll
    for (int i = 0; i < IPB; ++i) {
        const unsigned int* p = &smem[(i * 16 + osub * 4) * 64 + sseg[i] * 4];
        #pragma unroll
        for (int pq = 0; pq < 4; ++pq) {
            uint4 v = *(const uint4*)(p + pq * 64);
            acc[2*pq]   = __builtin_amdgcn_fdot2(__builtin_bit_cast(h2, v.x), cA[i],
                                                 acc[2*pq],   false);
            acc[2*pq]   = __builtin_amdgcn_fdot2(__builtin_bit_cast(h2, v.y), cB[i],
                                                 acc[2*pq],   false);
            acc[2*pq+1] = __builtin_amdgcn_fdot2(__builtin_bit_cast(h2, v.z), cA[i],
                                                 acc[2*pq+1], false);
            acc[2*pq+1] = __builtin_amdgcn_fdot2(__builtin_bit_cast(h2, v.w), cB[i],
                                                 acc[2*pq+1], false);
        }
    }

    // ---- LDS transpose (lane=b -> lane=o) + coalesced float4 partial stores ----
    __syncthreads();                      // weights no longer needed
    float* smf = (float*)smem;            // [128 b][33] fp32 = 16.9 KB
    const int b_l0 = bsub * 64 + lane;
    #pragma unroll
    for (int q = 0; q < 8; ++q)
        smf[b_l0 * 33 + osub * 8 + q] = acc[q];
    __syncthreads();

    const int qo = tid & 7;               // o-quad 0..7 (4 floats each)
    const int g  = tid >> 3;              // 0..63
    #pragma unroll
    for (int r = 0; r < 2; ++r) {
        int b_l = g + 64 * r;
        float4 v;
        v.x = smf[b_l * 33 + qo * 4 + 0];
        v.y = smf[b_l * 33 + qo * 4 + 1];
        v.z = smf[b_l * 33 + qo * 4 + 2];
        v.w = smf[b_l * 33 + qo * 4 + 3];
        *(float4*)(part + (size_t)isplit * (512 * 256)
                        + (size_t)(b_base + b_l) * 256 + o_base + qo * 4) = v;
    }
}

__global__ __launch_bounds__(256)
void pp_reduce(const float* __restrict__ part, float* __restrict__ out) {
    const size_t off4 = (size_t)blockIdx.x * 256 + threadIdx.x;  // float4 index
    const float4* p4 = (const float4*)part;
    float4 s = make_float4(0.f, 0.f, 0.f, 0.f);
    #pragma unroll
    for (int k = 0; k < NSPLIT; ++k) {
        float4 v = p4[(size_t)k * (512 * 64) + off4];
        s.x += v.x; s.y += v.y; s.z += v.z; s.w += v.w;
    }
    ((float4*)out)[off4] = s;
}

extern "C" void kernel_launch(void* const* d_in, const int* in_sizes, int n_in,
                              void* d_out, int out_size, void* d_ws, size_t ws_size,
                              hipStream_t stream) {
    const float* x = (const float*)d_in[0];
    const float* w = (const float*)d_in[1];
    float* out = (float*)d_out;
    unsigned int* we = (unsigned int*)d_ws;                       // 8.39 MB
    float* part = (float*)((char*)d_ws + (size_t)WE_UINTS * 4);   // 8.39 MB
    (void)ws_size; (void)n_in; (void)in_sizes; (void)out_size;

    pp_expand<<<dim3(256), 256, 0, stream>>>(w, we);
    pp_partial<<<dim3(NSPLIT, 8, 4), 512, 0, stream>>>(x, we, part);
    pp_reduce<<<dim3(128), 256, 0, stream>>>(part, out);   // 128*256 float4 = 131072 floats
}